// Round 7
// baseline (333.942 us; speedup 1.0000x reference)
//
#include <hip/hip_runtime.h>
#include <cstddef>
#include <cstdint>

#define TCNT 256

namespace {
constexpr int CIN    = 64;
constexpr int COUT   = 128;
constexpr int HDIM   = 64;
constexpr int WDIM   = 64;
constexpr int HW     = HDIM * WDIM;     // 4096
constexpr int KD     = CIN * 9;         // 576
constexpr int NOFF   = 2 * CIN * 9;     // 1152
constexpr int NTOT   = NOFF + CIN * 9;  // 1728
constexpr int NBATCH = 8;
constexpr int HXW    = 66;              // halo-padded spatial dim
constexpr int COPAD  = 1792;            // 14*128 padded co
constexpr int NGT    = COPAD / 16;      // 112 co-fragment tiles
constexpr float MAXOFF = 16.0f;         // max(H,W)/4

// d_ws layout (ushort elements for the fp16 region, then fp32 planes)
constexpr size_t XT_ELEMS = (size_t)NBATCH * HXW * HXW * 64;  // x hi only
constexpr size_t WP_ELEMS = (size_t)18 * NGT * 512;           // 1,032,192
constexpr size_t WC_ELEMS = (size_t)18 * 8 * 512;             // 73,728
constexpr size_t OFF_XFH  = 0;
constexpr size_t OFF_WPH  = XT_ELEMS;
constexpr size_t OFF_WPL  = XT_ELEMS + WP_ELEMS;
constexpr size_t OFF_WCH  = XT_ELEMS + 2 * WP_ELEMS;
constexpr size_t FIXED_BYTES = (XT_ELEMS + 2 * WP_ELEMS + WC_ELEMS) * 2;
}

typedef __attribute__((ext_vector_type(8))) short    s16x8;
typedef __attribute__((ext_vector_type(8))) _Float16 f16x8;
typedef __attribute__((ext_vector_type(4))) float    f32x4;

__device__ __forceinline__ unsigned short f2h(float v) {
  _Float16 h = (_Float16)v;                       // RNE
  return __builtin_bit_cast(unsigned short, h);
}
__device__ __forceinline__ float h2f(unsigned short u) {
  return (float)__builtin_bit_cast(_Float16, u);
}

// ---------------------------------------------------------------------------
// prep_x: x fp32 NCHW -> xFh fp16 (truncated operand), HWC with zero halo:
//   xF[b][yy 0..65][xx 0..65][c 0..63].   (unchanged from round 6)
// ---------------------------------------------------------------------------
__global__ __launch_bounds__(TCNT) void prep_x(
    const float* __restrict__ x, unsigned short* __restrict__ xFh)
{
  const int b  = blockIdx.y;
  const int yy = blockIdx.x;
  const int t  = threadIdx.x;
  unsigned short* oh = xFh + ((size_t)(b * HXW + yy)) * HXW * 64;
  if (yy == 0 || yy == HXW - 1) {
    for (int lin = t; lin < HXW * 64; lin += TCNT) oh[lin] = 0;
    return;
  }
  __shared__ float tile[64][65];
  const int y = yy - 1;
  #pragma unroll
  for (int i = 0; i < 4; ++i) {
    const int f = t + TCNT * i;          // 0..1023 float4s
    const int c = f >> 4, xq = f & 15;
    const float4 v =
        *(const float4*)(x + ((size_t)(b * 64 + c)) * HW + y * WDIM + xq * 4);
    tile[c][xq * 4 + 0] = v.x; tile[c][xq * 4 + 1] = v.y;
    tile[c][xq * 4 + 2] = v.z; tile[c][xq * 4 + 3] = v.w;
  }
  if (t < 128) {                          // zero halo columns xx=0, xx=65
    const int c = t & 63, xe = (t >> 6) ? (HXW - 1) * 64 : 0;
    oh[xe + c] = 0;
  }
  __syncthreads();
  const int xc = t >> 2, cg = (t & 3) * 16;
  s16x8 h0, h1;
  #pragma unroll
  for (int u = 0; u < 8; ++u) h0[u] = (short)f2h(tile[cg + u][xc]);
  #pragma unroll
  for (int u = 0; u < 8; ++u) h1[u] = (short)f2h(tile[cg + 8 + u][xc]);
  *(s16x8*)(oh + (xc + 1) * 64 + cg)     = h0;
  *(s16x8*)(oh + (xc + 1) * 64 + cg + 8) = h1;
}

// ---------------------------------------------------------------------------
// prep_w: w_off/w_mod -> FRAGMENT-ORDERED fp16 hi/lo:
//   wF1[h=r*2+ks][g 0..111][lane 0..63][f 0..7]
//     = w(co = g*16 + (lane&15), k = (ks*32 + (lane>>4)*8 + f)*9 + r)
//   A wave's B-fragment load becomes one coalesced 16B/lane read.
// ---------------------------------------------------------------------------
__global__ __launch_bounds__(TCNT) void prep_w(
    const float* __restrict__ w_off, const float* __restrict__ w_mod,
    unsigned short* __restrict__ wF1h, unsigned short* __restrict__ wF1l)
{
  const int g  = blockIdx.x;             // 0..111
  const int hh = blockIdx.y;             // 0..17 (= r*2+ks)
  const int r  = hh >> 1, ks = hh & 1;
  const int t  = threadIdx.x;
  const size_t base = ((size_t)hh * NGT + g) * 512;
  #pragma unroll
  for (int q = 0; q < 2; ++q) {
    const int e = t + q * 256;           // 0..511
    const int l = e >> 3, f = e & 7;
    const int co = g * 16 + (l & 15);
    const int c  = ks * 32 + (l >> 4) * 8 + f;
    float v = 0.f;
    if (co < NOFF)      v = w_off[(size_t)co * KD + c * 9 + r];
    else if (co < NTOT) v = w_mod[(size_t)(co - NOFF) * KD + c * 9 + r];
    const unsigned short hb = f2h(v);
    wF1h[base + e] = hb;
    wF1l[base + e] = f2h(v - h2f(hb));
  }
}

// ---------------------------------------------------------------------------
// prep_wc: w_conv -> fragment-ordered fp16 (truncated):
//   wF2[hh=sc*2+ks][nt 0..7][lane][f] = w_conv[nt*16+(lane&15)]
//                                          [sc*64+ks*32+(lane>>4)*8+f]
// ---------------------------------------------------------------------------
__global__ __launch_bounds__(TCNT) void prep_wc(
    const float* __restrict__ w_conv, unsigned short* __restrict__ wF2)
{
  const int nt = blockIdx.x;             // 0..7
  const int hh = blockIdx.y;             // 0..17
  const int sc = hh >> 1, ks = hh & 1;
  const int t  = threadIdx.x;
  const size_t base = ((size_t)hh * 8 + nt) * 512;
  #pragma unroll
  for (int q = 0; q < 2; ++q) {
    const int e = t + q * 256;
    const int l = e >> 3, f = e & 7;
    const int o = nt * 16 + (l & 15);
    const int c = sc * 64 + ks * 32 + (l >> 4) * 8 + f;
    wF2[base + e] = f2h(w_conv[(size_t)o * KD + c]);
  }
}

// ---------------------------------------------------------------------------
// Stage 1: offset+mask convs, fp16 2-term MFMA implicit-GEMM.
//   A: LDS ping-pong (2 x 8 KB), ONE barrier per 32-K half (18 total).
//   B: registers, loaded coalesced from fragment-ordered wF1 (no LDS).
// ---------------------------------------------------------------------------
__global__ __launch_bounds__(TCNT, 3) void dcn_stage1(
    const unsigned short* __restrict__ xFh,
    const unsigned short* __restrict__ wF1h, const unsigned short* __restrict__ wF1l,
    const float* __restrict__ b_off, const float* __restrict__ b_mod,
    float* __restrict__ ws, int b0, int nb)
{
  __shared__ unsigned short Ah[2][128][32];     // 16 KB

  const int t      = threadIdx.x;
  const int Mchunk = nb * HW;
  const int p0  = blockIdx.x * 128;          // chunk-local pixel base (2 rows)
  const int b   = b0 + (p0 >> 12);
  const int h0  = (p0 & (HW - 1)) >> 6;
  const int co0 = blockIdx.y * 128;

  // A staging role (16 halfs per thread per half-step)
  const int s_row = t >> 1;
  const int s_kh  = t & 1;
  const int s_sw  = ((s_row >> 1) & 3) << 3;
  const int a_h   = h0 + (s_row >> 6);       // halo row base (+ki)
  const int a_w   = s_row & 63;              // halo col base (+kj)
  const unsigned short* xbh = xFh + (size_t)b * HXW * HXW * 64;

  // MFMA role
  const int wave = t >> 6, lane = t & 63;
  const int wm = wave >> 1, wn = wave & 1;
  const int lrow = lane & 15;
  const int lkh  = lane >> 4;
  const int gbase = (co0 >> 4) + wn * 4;     // fragment co-tile base

  f32x4 acc[4][4];
  #pragma unroll
  for (int m = 0; m < 4; ++m)
    #pragma unroll
    for (int n = 0; n < 4; ++n) acc[m][n] = (f32x4)0.f;

  s16x8 rE0, rE1, rO0, rO1;                  // A reg staging (ping-pong)
  f16x8 wh[4], wl[4];                        // B fragments (current half)

#define ALOAD(D0, D1, H)                                                     \
  {                                                                          \
    const int r_  = (H) >> 1;                                                \
    const int ks_ = (H) & 1;                                                 \
    const int ki_ = r_ / 3;                                                  \
    const int kj_ = r_ - 3 * ki_;                                            \
    const size_t aoff_ = ((size_t)((a_h + ki_) * HXW + (a_w + kj_))) * 64 +  \
                         ks_ * 32 + s_kh * 16;                               \
    D0 = *(const s16x8*)(xbh + aoff_);                                       \
    D1 = *(const s16x8*)(xbh + aoff_ + 8);                                   \
  }

#define AWRITE(S0, S1, SEL)                                                  \
  {                                                                          \
    const int c0_ = (s_kh * 16) ^ s_sw;                                      \
    const int c1_ = (s_kh * 16 + 8) ^ s_sw;                                  \
    *(s16x8*)&Ah[SEL][s_row][c0_] = S0;                                      \
    *(s16x8*)&Ah[SEL][s_row][c1_] = S1;                                      \
  }

#define WLOAD(H)                                                             \
  {                                                                          \
    _Pragma("unroll")                                                        \
    for (int n = 0; n < 4; ++n) {                                            \
      const size_t o_ = ((size_t)(H) * NGT + gbase + n) * 512 + lane * 8;    \
      wh[n] = *(const f16x8*)(wF1h + o_);                                    \
      wl[n] = *(const f16x8*)(wF1l + o_);                                    \
    }                                                                        \
  }

#define MFMA_P(SEL)                                                          \
  {                                                                          \
    f16x8 fa[4];                                                             \
    _Pragma("unroll")                                                        \
    for (int m = 0; m < 4; ++m) {                                            \
      const int row = wm * 64 + m * 16 + lrow;                               \
      const int col = (lkh * 8) ^ (((row >> 1) & 3) << 3);                   \
      fa[m] = *(const f16x8*)&Ah[SEL][row][col];                             \
    }                                                                        \
    _Pragma("unroll")                                                        \
    for (int n = 0; n < 4; ++n) {                                            \
      _Pragma("unroll")                                                      \
      for (int m = 0; m < 4; ++m) {                                          \
        acc[m][n] = __builtin_amdgcn_mfma_f32_16x16x32_f16(fa[m], wh[n], acc[m][n], 0, 0, 0); \
        acc[m][n] = __builtin_amdgcn_mfma_f32_16x16x32_f16(fa[m], wl[n], acc[m][n], 0, 0, 0); \
      }                                                                      \
    }                                                                        \
  }

  // preamble: half 0 into LDS buf0; half 1 into regs; W(0) into regs
  ALOAD(rE0, rE1, 0)
  WLOAD(0)
  AWRITE(rE0, rE1, 0)
  ALOAD(rO0, rO1, 1)
  __syncthreads();

  #pragma unroll 1
  for (int h = 0; h < 17; ++h) {
    MFMA_P(h & 1)                        // consume current half
    WLOAD(h + 1)                         // B frags for next half (after MFMA read)
    if ((h & 1) == 0) {                  // stage A for h+1, prefetch h+2
      AWRITE(rO0, rO1, 1)
      if (h < 16) ALOAD(rE0, rE1, h + 2)
    } else {
      AWRITE(rE0, rE1, 0)
      if (h < 16) ALOAD(rO0, rO1, h + 2)
    }
    __syncthreads();
  }
  MFMA_P(1)                              // final half (h=17)

  // Epilogue: bias, clip (offset region), store plane-major. (unchanged)
  const bool isOff = (co0 < NOFF);
  #pragma unroll
  for (int n = 0; n < 4; ++n) {
    const int cog = co0 + wn * 64 + n * 16 + lrow;
    if (cog >= NTOT) continue;
    const float bias = isOff ? b_off[cog] : b_mod[cog - NOFF];
    float* oplane = ws + (size_t)cog * Mchunk;
    #pragma unroll
    for (int m = 0; m < 4; ++m) {
      f32x4 v = acc[m][n];
      float4 o;
      o.x = v[0] + bias; o.y = v[1] + bias; o.z = v[2] + bias; o.w = v[3] + bias;
      if (isOff) {
        o.x = fminf(MAXOFF, fmaxf(-MAXOFF, o.x));
        o.y = fminf(MAXOFF, fmaxf(-MAXOFF, o.y));
        o.z = fminf(MAXOFF, fmaxf(-MAXOFF, o.z));
        o.w = fminf(MAXOFF, fmaxf(-MAXOFF, o.w));
      }
      const int pb = p0 + wm * 64 + m * 16 + lkh * 4;
      *(float4*)(oplane + pb) = o;
    }
  }
#undef ALOAD
#undef AWRITE
#undef WLOAD
#undef MFMA_P
}

// ---------------------------------------------------------------------------
// Stage 2: fp32 bilinear sampling + fp16 2-term MFMA einsum.
//   Samples: LDS ping-pong (16 KB total), ONE barrier per sc (9 total).
//   W: registers from fragment-ordered wF2 (no LDS). MFMA issued before the
//   long sampling phase each iteration (matrix pipe runs under gathers).
// ---------------------------------------------------------------------------
__global__ __launch_bounds__(TCNT, 4) void dcn_stage2(
    const float* __restrict__ x, const float* __restrict__ planes,
    const unsigned short* __restrict__ wF2,
    float* __restrict__ out, int b0, int nb)
{
  __shared__ unsigned short SH[2][32][64], SL[2][32][64];   // 16 KB

  const int t      = threadIdx.x;
  const int Mchunk = nb * HW;
  const int pc0 = blockIdx.x * 32;           // chunk-local pixel base
  const int b   = b0 + (pc0 >> 12);
  const int h   = (pc0 & (HW - 1)) >> 6;
  const int w0  = pc0 & 63;                  // 0 or 32

  const int tpx = t & 31;
  const int tsg = t >> 5;                    // 0..7 -> sl block of 8
  const int a_swz = (tpx & 7) << 3;
  const float* ws_pix = planes + pc0 + tpx;
  const float* xb     = x + (size_t)b * CIN * HW;

  const int wave = t >> 6, lane = t & 63;
  const int lrow = lane & 15, lkh = lane >> 4;
  const int f_swz = (lrow & 7) << 3;

  f32x4 acc[2][2];
  #pragma unroll
  for (int m = 0; m < 2; ++m)
    #pragma unroll
    for (int n = 0; n < 2; ++n) acc[m][n] = (f32x4)0.f;

  float vals[8];
  f16x8 w4[4];                               // [ks*2+n]

#define SAMPLE(SCC)                                                          \
  {                                                                          \
    _Pragma("unroll")                                                        \
    for (int j = 0; j < 8; ++j) {                                            \
      const int sl = tsg * 8 + j;                                            \
      const int s  = (SCC) * 64 + sl;                                        \
      const int c  = s / 9;                                                  \
      const int kk = s - c * 9;                                              \
      const int ki = kk / 3;                                                 \
      const int kj = kk - ki * 3;                                            \
      const float dy = ws_pix[(size_t)(2 * s)     * Mchunk];                 \
      const float dx = ws_pix[(size_t)(2 * s + 1) * Mchunk];                 \
      const float m  = ws_pix[(size_t)(NOFF + s)  * Mchunk];                 \
      const float py = dy + (float)(h + ki - 1);                             \
      const float px = dx + (float)(w0 + tpx + kj - 1);                      \
      const bool valid = (py > -1.f) && (py < (float)HDIM) &&                \
                         (px > -1.f) && (px < (float)WDIM);                  \
      const float y0f = floorf(py), x0f = floorf(px);                        \
      const float wy = py - y0f, wx = px - x0f;                              \
      const int y0 = (int)y0f, x0 = (int)x0f;                                \
      const float* plane = xb + c * HW;                                      \
      float v00 = 0.f, v01 = 0.f, v10 = 0.f, v11 = 0.f;                      \
      if ((unsigned)y0 < (unsigned)HDIM) {                                   \
        const float* row = plane + (y0 << 6);                                \
        if ((unsigned)x0       < (unsigned)WDIM) v00 = row[x0];              \
        if ((unsigned)(x0 + 1) < (unsigned)WDIM) v01 = row[x0 + 1];          \
      }                                                                      \
      if ((unsigned)(y0 + 1) < (unsigned)HDIM) {                             \
        const float* row = plane + ((y0 + 1) << 6);                          \
        if ((unsigned)x0       < (unsigned)WDIM) v10 = row[x0];              \
        if ((unsigned)(x0 + 1) < (unsigned)WDIM) v11 = row[x0 + 1];          \
      }                                                                      \
      const float val = (1.f - wy) * ((1.f - wx) * v00 + wx * v01)           \
                      + wy         * ((1.f - wx) * v10 + wx * v11);          \
      vals[j] = valid ? val * m : 0.f;                                       \
    }                                                                        \
  }

#define PACK(SEL)                                                            \
  {                                                                          \
    s16x8 h8, l8;                                                            \
    _Pragma("unroll")                                                        \
    for (int u = 0; u < 8; ++u) {                                            \
      const unsigned short hb = f2h(vals[u]);                                \
      h8[u] = (short)hb;                                                     \
      l8[u] = (short)f2h(vals[u] - h2f(hb));                                 \
    }                                                                        \
    const int col = (tsg * 8) ^ a_swz;                                       \
    *(s16x8*)&SH[SEL][tpx][col] = h8;                                        \
    *(s16x8*)&SL[SEL][tpx][col] = l8;                                        \
  }

#define W2LOAD(SCC)                                                          \
  {                                                                          \
    _Pragma("unroll")                                                        \
    for (int ks = 0; ks < 2; ++ks)                                           \
      _Pragma("unroll")                                                      \
      for (int n = 0; n < 2; ++n) {                                          \
        const size_t o_ = (((size_t)(SCC) * 2 + ks) * 8 + wave * 2 + n) * 512\
                          + lane * 8;                                        \
        w4[ks * 2 + n] = *(const f16x8*)(wF2 + o_);                          \
      }                                                                      \
  }

#define MFMA2(SEL)                                                           \
  {                                                                          \
    _Pragma("unroll")                                                        \
    for (int ks = 0; ks < 2; ++ks) {                                         \
      const int colb = (ks * 32 + lkh * 8) ^ f_swz;                          \
      f16x8 fah[2], fal[2];                                                  \
      _Pragma("unroll")                                                      \
      for (int m = 0; m < 2; ++m) {                                          \
        fah[m] = *(const f16x8*)&SH[SEL][m * 16 + lrow][colb];               \
        fal[m] = *(const f16x8*)&SL[SEL][m * 16 + lrow][colb];               \
      }                                                                      \
      _Pragma("unroll")                                                      \
      for (int n = 0; n < 2; ++n) {                                          \
        _Pragma("unroll")                                                    \
        for (int m = 0; m < 2; ++m) {                                        \
          acc[m][n] = __builtin_amdgcn_mfma_f32_16x16x32_f16(fah[m], w4[ks * 2 + n], acc[m][n], 0, 0, 0); \
          acc[m][n] = __builtin_amdgcn_mfma_f32_16x16x32_f16(fal[m], w4[ks * 2 + n], acc[m][n], 0, 0, 0); \
        }                                                                    \
      }                                                                      \
    }                                                                        \
  }

  // preamble
  SAMPLE(0)
  PACK(0)
  W2LOAD(0)
  __syncthreads();

  #pragma unroll 1
  for (int sc = 0; sc < 8; ++sc) {
    MFMA2(sc & 1)                        // consume sc (matrix pipe busy...)
    W2LOAD(sc + 1)                       // (after MFMA has read w4)
    SAMPLE(sc + 1)                       // ...while gathers/VALU run
    PACK((sc + 1) & 1)
    __syncthreads();
  }
  MFMA2(0)                               // sc = 8

  // Epilogue: D col(lane&15) = out-channel, row((lane>>4)*4+reg) = pixel.
  #pragma unroll
  for (int n = 0; n < 2; ++n) {
    const int o = wave * 32 + n * 16 + lrow;
    float* obase = out + ((size_t)(b * COUT + o)) * HW + h * WDIM + w0;
    #pragma unroll
    for (int m = 0; m < 2; ++m) {
      const int pxl = m * 16 + lkh * 4;
      f32x4 v = acc[m][n];
      *(float4*)(obase + pxl) = make_float4(v[0], v[1], v[2], v[3]);
    }
  }
#undef SAMPLE
#undef PACK
#undef W2LOAD
#undef MFMA2
}

// ---------------------------------------------------------------------------
extern "C" void kernel_launch(void* const* d_in, const int* in_sizes, int n_in,
                              void* d_out, int out_size, void* d_ws, size_t ws_size,
                              hipStream_t stream) {
  (void)in_sizes; (void)n_in; (void)out_size;
  const float* x      = (const float*)d_in[0];
  const float* w_off  = (const float*)d_in[1];
  const float* b_off  = (const float*)d_in[2];
  const float* w_mod  = (const float*)d_in[3];
  const float* b_mod  = (const float*)d_in[4];
  const float* w_conv = (const float*)d_in[5];
  float* out = (float*)d_out;

  unsigned short* wsu = (unsigned short*)d_ws;
  unsigned short* xFh  = wsu + OFF_XFH;
  unsigned short* wF1h = wsu + OFF_WPH;
  unsigned short* wF1l = wsu + OFF_WPL;
  unsigned short* wF2  = wsu + OFF_WCH;
  float* planes = (float*)((char*)d_ws + FIXED_BYTES);

  const size_t ws_per_batch = (size_t)NTOT * HW * sizeof(float);  // 28.3 MB
  size_t avail = (ws_size > FIXED_BYTES) ? (ws_size - FIXED_BYTES) : 0;
  int nb = (int)(avail / ws_per_batch);
  if (nb < 1) nb = 1;
  if (nb > NBATCH) nb = NBATCH;

  prep_x<<<dim3(HXW, NBATCH), TCNT, 0, stream>>>(x, xFh);
  prep_w<<<dim3(NGT, 18), TCNT, 0, stream>>>(w_off, w_mod, wF1h, wF1l);
  prep_wc<<<dim3(8, 18), TCNT, 0, stream>>>(w_conv, wF2);

  for (int b0 = 0; b0 < NBATCH; b0 += nb) {
    const int cur = (NBATCH - b0 < nb) ? (NBATCH - b0) : nb;
    dim3 g1(cur * 32, 14);   // pixel tiles x co tiles (14*128 = 1792 >= 1728)
    dcn_stage1<<<g1, TCNT, 0, stream>>>(xFh, wF1h, wF1l, b_off, b_mod,
                                        planes, b0, cur);
    dcn_stage2<<<cur * 128, TCNT, 0, stream>>>(x, planes, wF2, out, b0, cur);
  }
}

// Round 8
// 303.139 us; speedup vs baseline: 1.1016x; 1.1016x over previous
//
#include <hip/hip_runtime.h>
#include <cstddef>
#include <cstdint>

#define TCNT 256

namespace {
constexpr int CIN    = 64;
constexpr int COUT   = 128;
constexpr int HDIM   = 64;
constexpr int WDIM   = 64;
constexpr int HW     = HDIM * WDIM;     // 4096
constexpr int KD     = CIN * 9;         // 576
constexpr int NOFF   = 2 * CIN * 9;     // 1152
constexpr int NTOT   = NOFF + CIN * 9;  // 1728
constexpr int NBATCH = 8;
constexpr int HXW    = 66;              // halo-padded spatial dim
constexpr int COPAD  = 1792;            // 14*128 padded co
constexpr int NGT    = COPAD / 16;      // 112 co-fragment tiles
constexpr float MAXOFF = 16.0f;         // max(H,W)/4

// d_ws layout (ushort elements for the fp16 region, then fp32 planes)
constexpr size_t XT_ELEMS = (size_t)NBATCH * HXW * HXW * 64;  // x hi only
constexpr size_t WP_ELEMS = (size_t)18 * NGT * 512;           // 1,032,192
constexpr size_t WC_ELEMS = (size_t)18 * 8 * 512;             // 73,728
constexpr size_t OFF_XFH  = 0;
constexpr size_t OFF_WPH  = XT_ELEMS;
constexpr size_t OFF_WPL  = XT_ELEMS + WP_ELEMS;
constexpr size_t OFF_WCH  = XT_ELEMS + 2 * WP_ELEMS;
constexpr size_t FIXED_BYTES = (XT_ELEMS + 2 * WP_ELEMS + WC_ELEMS) * 2;
}

typedef __attribute__((ext_vector_type(8))) short    s16x8;
typedef __attribute__((ext_vector_type(8))) _Float16 f16x8;
typedef __attribute__((ext_vector_type(4))) float    f32x4;

__device__ __forceinline__ unsigned short f2h(float v) {
  _Float16 h = (_Float16)v;                       // RNE
  return __builtin_bit_cast(unsigned short, h);
}
__device__ __forceinline__ float h2f(unsigned short u) {
  return (float)__builtin_bit_cast(_Float16, u);
}

// ---------------------------------------------------------------------------
// prep_x: x fp32 NCHW -> xFh fp16 (truncated operand), HWC with zero halo:
//   xF[b][yy 0..65][xx 0..65][c 0..63].   (unchanged)
// ---------------------------------------------------------------------------
__global__ __launch_bounds__(TCNT) void prep_x(
    const float* __restrict__ x, unsigned short* __restrict__ xFh)
{
  const int b  = blockIdx.y;
  const int yy = blockIdx.x;
  const int t  = threadIdx.x;
  unsigned short* oh = xFh + ((size_t)(b * HXW + yy)) * HXW * 64;
  if (yy == 0 || yy == HXW - 1) {
    for (int lin = t; lin < HXW * 64; lin += TCNT) oh[lin] = 0;
    return;
  }
  __shared__ float tile[64][65];
  const int y = yy - 1;
  #pragma unroll
  for (int i = 0; i < 4; ++i) {
    const int f = t + TCNT * i;          // 0..1023 float4s
    const int c = f >> 4, xq = f & 15;
    const float4 v =
        *(const float4*)(x + ((size_t)(b * 64 + c)) * HW + y * WDIM + xq * 4);
    tile[c][xq * 4 + 0] = v.x; tile[c][xq * 4 + 1] = v.y;
    tile[c][xq * 4 + 2] = v.z; tile[c][xq * 4 + 3] = v.w;
  }
  if (t < 128) {                          // zero halo columns xx=0, xx=65
    const int c = t & 63, xe = (t >> 6) ? (HXW - 1) * 64 : 0;
    oh[xe + c] = 0;
  }
  __syncthreads();
  const int xc = t >> 2, cg = (t & 3) * 16;
  s16x8 h0, h1;
  #pragma unroll
  for (int u = 0; u < 8; ++u) h0[u] = (short)f2h(tile[cg + u][xc]);
  #pragma unroll
  for (int u = 0; u < 8; ++u) h1[u] = (short)f2h(tile[cg + 8 + u][xc]);
  *(s16x8*)(oh + (xc + 1) * 64 + cg)     = h0;
  *(s16x8*)(oh + (xc + 1) * 64 + cg + 8) = h1;
}

// ---------------------------------------------------------------------------
// prep_w: w_off/w_mod -> FRAGMENT-ORDERED fp16 hi/lo.  (unchanged)
// ---------------------------------------------------------------------------
__global__ __launch_bounds__(TCNT) void prep_w(
    const float* __restrict__ w_off, const float* __restrict__ w_mod,
    unsigned short* __restrict__ wF1h, unsigned short* __restrict__ wF1l)
{
  const int g  = blockIdx.x;             // 0..111
  const int hh = blockIdx.y;             // 0..17 (= r*2+ks)
  const int r  = hh >> 1, ks = hh & 1;
  const int t  = threadIdx.x;
  const size_t base = ((size_t)hh * NGT + g) * 512;
  #pragma unroll
  for (int q = 0; q < 2; ++q) {
    const int e = t + q * 256;           // 0..511
    const int l = e >> 3, f = e & 7;
    const int co = g * 16 + (l & 15);
    const int c  = ks * 32 + (l >> 4) * 8 + f;
    float v = 0.f;
    if (co < NOFF)      v = w_off[(size_t)co * KD + c * 9 + r];
    else if (co < NTOT) v = w_mod[(size_t)(co - NOFF) * KD + c * 9 + r];
    const unsigned short hb = f2h(v);
    wF1h[base + e] = hb;
    wF1l[base + e] = f2h(v - h2f(hb));
  }
}

// ---------------------------------------------------------------------------
// prep_wc: w_conv -> fragment-ordered fp16 (truncated).  (unchanged)
// ---------------------------------------------------------------------------
__global__ __launch_bounds__(TCNT) void prep_wc(
    const float* __restrict__ w_conv, unsigned short* __restrict__ wF2)
{
  const int nt = blockIdx.x;             // 0..7
  const int hh = blockIdx.y;             // 0..17
  const int sc = hh >> 1, ks = hh & 1;
  const int t  = threadIdx.x;
  const size_t base = ((size_t)hh * 8 + nt) * 512;
  #pragma unroll
  for (int q = 0; q < 2; ++q) {
    const int e = t + q * 256;
    const int l = e >> 3, f = e & 7;
    const int o = nt * 16 + (l & 15);
    const int c = sc * 64 + ks * 32 + (l >> 4) * 8 + f;
    wF2[base + e] = f2h(w_conv[(size_t)o * KD + c]);
  }
}

// ---------------------------------------------------------------------------
// Stage 1: offset+mask convs, fp16 2-term MFMA implicit-GEMM.
//   (byte-identical to round 7: 154 us, MfmaUtil 38%, 0 conflicts)
// ---------------------------------------------------------------------------
__global__ __launch_bounds__(TCNT, 3) void dcn_stage1(
    const unsigned short* __restrict__ xFh,
    const unsigned short* __restrict__ wF1h, const unsigned short* __restrict__ wF1l,
    const float* __restrict__ b_off, const float* __restrict__ b_mod,
    float* __restrict__ ws, int b0, int nb)
{
  __shared__ unsigned short Ah[2][128][32];     // 16 KB

  const int t      = threadIdx.x;
  const int Mchunk = nb * HW;
  const int p0  = blockIdx.x * 128;          // chunk-local pixel base (2 rows)
  const int b   = b0 + (p0 >> 12);
  const int h0  = (p0 & (HW - 1)) >> 6;
  const int co0 = blockIdx.y * 128;

  const int s_row = t >> 1;
  const int s_kh  = t & 1;
  const int s_sw  = ((s_row >> 1) & 3) << 3;
  const int a_h   = h0 + (s_row >> 6);       // halo row base (+ki)
  const int a_w   = s_row & 63;              // halo col base (+kj)
  const unsigned short* xbh = xFh + (size_t)b * HXW * HXW * 64;

  const int wave = t >> 6, lane = t & 63;
  const int wm = wave >> 1, wn = wave & 1;
  const int lrow = lane & 15;
  const int lkh  = lane >> 4;
  const int gbase = (co0 >> 4) + wn * 4;     // fragment co-tile base

  f32x4 acc[4][4];
  #pragma unroll
  for (int m = 0; m < 4; ++m)
    #pragma unroll
    for (int n = 0; n < 4; ++n) acc[m][n] = (f32x4)0.f;

  s16x8 rE0, rE1, rO0, rO1;                  // A reg staging (ping-pong)
  f16x8 wh[4], wl[4];                        // B fragments (current half)

#define ALOAD(D0, D1, H)                                                     \
  {                                                                          \
    const int r_  = (H) >> 1;                                                \
    const int ks_ = (H) & 1;                                                 \
    const int ki_ = r_ / 3;                                                  \
    const int kj_ = r_ - 3 * ki_;                                            \
    const size_t aoff_ = ((size_t)((a_h + ki_) * HXW + (a_w + kj_))) * 64 +  \
                         ks_ * 32 + s_kh * 16;                               \
    D0 = *(const s16x8*)(xbh + aoff_);                                       \
    D1 = *(const s16x8*)(xbh + aoff_ + 8);                                   \
  }

#define AWRITE(S0, S1, SEL)                                                  \
  {                                                                          \
    const int c0_ = (s_kh * 16) ^ s_sw;                                      \
    const int c1_ = (s_kh * 16 + 8) ^ s_sw;                                  \
    *(s16x8*)&Ah[SEL][s_row][c0_] = S0;                                      \
    *(s16x8*)&Ah[SEL][s_row][c1_] = S1;                                      \
  }

#define WLOAD(H)                                                             \
  {                                                                          \
    _Pragma("unroll")                                                        \
    for (int n = 0; n < 4; ++n) {                                            \
      const size_t o_ = ((size_t)(H) * NGT + gbase + n) * 512 + lane * 8;    \
      wh[n] = *(const f16x8*)(wF1h + o_);                                    \
      wl[n] = *(const f16x8*)(wF1l + o_);                                    \
    }                                                                        \
  }

#define MFMA_P(SEL)                                                          \
  {                                                                          \
    f16x8 fa[4];                                                             \
    _Pragma("unroll")                                                        \
    for (int m = 0; m < 4; ++m) {                                            \
      const int row = wm * 64 + m * 16 + lrow;                               \
      const int col = (lkh * 8) ^ (((row >> 1) & 3) << 3);                   \
      fa[m] = *(const f16x8*)&Ah[SEL][row][col];                             \
    }                                                                        \
    _Pragma("unroll")                                                        \
    for (int n = 0; n < 4; ++n) {                                            \
      _Pragma("unroll")                                                      \
      for (int m = 0; m < 4; ++m) {                                          \
        acc[m][n] = __builtin_amdgcn_mfma_f32_16x16x32_f16(fa[m], wh[n], acc[m][n], 0, 0, 0); \
        acc[m][n] = __builtin_amdgcn_mfma_f32_16x16x32_f16(fa[m], wl[n], acc[m][n], 0, 0, 0); \
      }                                                                      \
    }                                                                        \
  }

  // preamble: half 0 into LDS buf0; half 1 into regs; W(0) into regs
  ALOAD(rE0, rE1, 0)
  WLOAD(0)
  AWRITE(rE0, rE1, 0)
  ALOAD(rO0, rO1, 1)
  __syncthreads();

  #pragma unroll 1
  for (int h = 0; h < 17; ++h) {
    MFMA_P(h & 1)                        // consume current half
    WLOAD(h + 1)                         // B frags for next half (after MFMA read)
    if ((h & 1) == 0) {                  // stage A for h+1, prefetch h+2
      AWRITE(rO0, rO1, 1)
      if (h < 16) ALOAD(rE0, rE1, h + 2)
    } else {
      AWRITE(rE0, rE1, 0)
      if (h < 16) ALOAD(rO0, rO1, h + 2)
    }
    __syncthreads();
  }
  MFMA_P(1)                              // final half (h=17)

  // Epilogue: bias, clip (offset region), store plane-major.
  const bool isOff = (co0 < NOFF);
  #pragma unroll
  for (int n = 0; n < 4; ++n) {
    const int cog = co0 + wn * 64 + n * 16 + lrow;
    if (cog >= NTOT) continue;
    const float bias = isOff ? b_off[cog] : b_mod[cog - NOFF];
    float* oplane = ws + (size_t)cog * Mchunk;
    #pragma unroll
    for (int m = 0; m < 4; ++m) {
      f32x4 v = acc[m][n];
      float4 o;
      o.x = v[0] + bias; o.y = v[1] + bias; o.z = v[2] + bias; o.w = v[3] + bias;
      if (isOff) {
        o.x = fminf(MAXOFF, fmaxf(-MAXOFF, o.x));
        o.y = fminf(MAXOFF, fmaxf(-MAXOFF, o.y));
        o.z = fminf(MAXOFF, fmaxf(-MAXOFF, o.z));
        o.w = fminf(MAXOFF, fmaxf(-MAXOFF, o.w));
      }
      const int pb = p0 + wm * 64 + m * 16 + lkh * 4;
      *(float4*)(oplane + pb) = o;
    }
  }
#undef ALOAD
#undef AWRITE
#undef WLOAD
#undef MFMA_P
}

// ---------------------------------------------------------------------------
// Stage 2 (v3): fp32 sampling + fp16 2-term MFMA einsum.
//   Fixes vs round 7: NO forced min-occupancy (avoid spills); W fragments
//   DOUBLE-buffered (w4A/w4B) so next-W and next-sample loads issue before
//   the MFMA cluster (T14). One barrier per sc, samples ping-pong in LDS.
// ---------------------------------------------------------------------------
__global__ __launch_bounds__(TCNT) void dcn_stage2(
    const float* __restrict__ x, const float* __restrict__ planes,
    const unsigned short* __restrict__ wF2,
    float* __restrict__ out, int b0, int nb)
{
  __shared__ unsigned short SH[2][32][64], SL[2][32][64];   // 16 KB

  const int t      = threadIdx.x;
  const int Mchunk = nb * HW;
  const int pc0 = blockIdx.x * 32;           // chunk-local pixel base
  const int b   = b0 + (pc0 >> 12);
  const int h   = (pc0 & (HW - 1)) >> 6;
  const int w0  = pc0 & 63;                  // 0 or 32

  const int tpx = t & 31;
  const int tsg = t >> 5;                    // 0..7 -> sl block of 8
  const int a_swz = (tpx & 7) << 3;
  const float* ws_pix = planes + pc0 + tpx;
  const float* xb     = x + (size_t)b * CIN * HW;

  const int wave = t >> 6, lane = t & 63;
  const int lrow = lane & 15, lkh = lane >> 4;
  const int f_swz = (lrow & 7) << 3;

  f32x4 acc[2][2];
  #pragma unroll
  for (int m = 0; m < 2; ++m)
    #pragma unroll
    for (int n = 0; n < 2; ++n) acc[m][n] = (f32x4)0.f;

  float vals[8];
  f16x8 w4A[4], w4B[4];                      // W fragments, double-buffered

#define SAMPLE(SCC)                                                          \
  {                                                                          \
    _Pragma("unroll")                                                        \
    for (int j = 0; j < 8; ++j) {                                            \
      const int sl = tsg * 8 + j;                                            \
      const int s  = (SCC) * 64 + sl;                                        \
      const int c  = s / 9;                                                  \
      const int kk = s - c * 9;                                              \
      const int ki = kk / 3;                                                 \
      const int kj = kk - ki * 3;                                            \
      const float dy = ws_pix[(size_t)(2 * s)     * Mchunk];                 \
      const float dx = ws_pix[(size_t)(2 * s + 1) * Mchunk];                 \
      const float m  = ws_pix[(size_t)(NOFF + s)  * Mchunk];                 \
      const float py = dy + (float)(h + ki - 1);                             \
      const float px = dx + (float)(w0 + tpx + kj - 1);                      \
      const bool valid = (py > -1.f) && (py < (float)HDIM) &&                \
                         (px > -1.f) && (px < (float)WDIM);                  \
      const float y0f = floorf(py), x0f = floorf(px);                        \
      const float wy = py - y0f, wx = px - x0f;                              \
      const int y0 = (int)y0f, x0 = (int)x0f;                                \
      const float* plane = xb + c * HW;                                      \
      float v00 = 0.f, v01 = 0.f, v10 = 0.f, v11 = 0.f;                      \
      if ((unsigned)y0 < (unsigned)HDIM) {                                   \
        const float* row = plane + (y0 << 6);                                \
        if ((unsigned)x0       < (unsigned)WDIM) v00 = row[x0];              \
        if ((unsigned)(x0 + 1) < (unsigned)WDIM) v01 = row[x0 + 1];          \
      }                                                                      \
      if ((unsigned)(y0 + 1) < (unsigned)HDIM) {                             \
        const float* row = plane + ((y0 + 1) << 6);                          \
        if ((unsigned)x0       < (unsigned)WDIM) v10 = row[x0];              \
        if ((unsigned)(x0 + 1) < (unsigned)WDIM) v11 = row[x0 + 1];          \
      }                                                                      \
      const float val = (1.f - wy) * ((1.f - wx) * v00 + wx * v01)           \
                      + wy         * ((1.f - wx) * v10 + wx * v11);          \
      vals[j] = valid ? val * m : 0.f;                                       \
    }                                                                        \
  }

#define PACK(SEL)                                                            \
  {                                                                          \
    s16x8 h8, l8;                                                            \
    _Pragma("unroll")                                                        \
    for (int u = 0; u < 8; ++u) {                                            \
      const unsigned short hb = f2h(vals[u]);                                \
      h8[u] = (short)hb;                                                     \
      l8[u] = (short)f2h(vals[u] - h2f(hb));                                 \
    }                                                                        \
    const int col = (tsg * 8) ^ a_swz;                                       \
    *(s16x8*)&SH[SEL][tpx][col] = h8;                                        \
    *(s16x8*)&SL[SEL][tpx][col] = l8;                                        \
  }

#define W2LOAD(DST, SCC)                                                     \
  {                                                                          \
    _Pragma("unroll")                                                        \
    for (int ks = 0; ks < 2; ++ks)                                           \
      _Pragma("unroll")                                                      \
      for (int n = 0; n < 2; ++n) {                                          \
        const size_t o_ = (((size_t)(SCC) * 2 + ks) * 8 + wave * 2 + n) * 512\
                          + lane * 8;                                        \
        DST[ks * 2 + n] = *(const f16x8*)(wF2 + o_);                         \
      }                                                                      \
  }

#define MFMA2(SEL, WREG)                                                     \
  {                                                                          \
    _Pragma("unroll")                                                        \
    for (int ks = 0; ks < 2; ++ks) {                                         \
      const int colb = (ks * 32 + lkh * 8) ^ f_swz;                          \
      f16x8 fah[2], fal[2];                                                  \
      _Pragma("unroll")                                                      \
      for (int m = 0; m < 2; ++m) {                                          \
        fah[m] = *(const f16x8*)&SH[SEL][m * 16 + lrow][colb];               \
        fal[m] = *(const f16x8*)&SL[SEL][m * 16 + lrow][colb];               \
      }                                                                      \
      _Pragma("unroll")                                                      \
      for (int n = 0; n < 2; ++n) {                                          \
        _Pragma("unroll")                                                    \
        for (int m = 0; m < 2; ++m) {                                        \
          acc[m][n] = __builtin_amdgcn_mfma_f32_16x16x32_f16(fah[m], WREG[ks * 2 + n], acc[m][n], 0, 0, 0); \
          acc[m][n] = __builtin_amdgcn_mfma_f32_16x16x32_f16(fal[m], WREG[ks * 2 + n], acc[m][n], 0, 0, 0); \
        }                                                                    \
      }                                                                      \
    }                                                                        \
  }

  // preamble: sc=0 samples into SH[0]; W(0) into w4A
  SAMPLE(0)
  PACK(0)
  W2LOAD(w4A, 0)
  __syncthreads();

  #pragma unroll 1
  for (int it = 0; it < 4; ++it) {
    const int sce = 2 * it;              // even sc being consumed
    // phase A: consume sce (SH[0], w4A); produce sce+1 into SH[1]
    W2LOAD(w4B, sce + 1)                 // next-W issued early
    SAMPLE(sce + 1)                      // gather loads issued early
    MFMA2(0, w4A)                        // matrix pipe under the gathers
    PACK(1)
    __syncthreads();
    // phase B: consume sce+1 (SH[1], w4B); produce sce+2 into SH[0]
    W2LOAD(w4A, sce + 2)
    SAMPLE(sce + 2)
    MFMA2(1, w4B)
    PACK(0)
    __syncthreads();
  }
  MFMA2(0, w4A)                          // sc = 8

  // Epilogue: D col(lane&15) = out-channel, row((lane>>4)*4+reg) = pixel.
  #pragma unroll
  for (int n = 0; n < 2; ++n) {
    const int o = wave * 32 + n * 16 + lrow;
    float* obase = out + ((size_t)(b * COUT + o)) * HW + h * WDIM + w0;
    #pragma unroll
    for (int m = 0; m < 2; ++m) {
      const int pxl = m * 16 + lkh * 4;
      f32x4 v = acc[m][n];
      *(float4*)(obase + pxl) = make_float4(v[0], v[1], v[2], v[3]);
    }
  }
#undef SAMPLE
#undef PACK
#undef W2LOAD
#undef MFMA2
}

// ---------------------------------------------------------------------------
extern "C" void kernel_launch(void* const* d_in, const int* in_sizes, int n_in,
                              void* d_out, int out_size, void* d_ws, size_t ws_size,
                              hipStream_t stream) {
  (void)in_sizes; (void)n_in; (void)out_size;
  const float* x      = (const float*)d_in[0];
  const float* w_off  = (const float*)d_in[1];
  const float* b_off  = (const float*)d_in[2];
  const float* w_mod  = (const float*)d_in[3];
  const float* b_mod  = (const float*)d_in[4];
  const float* w_conv = (const float*)d_in[5];
  float* out = (float*)d_out;

  unsigned short* wsu = (unsigned short*)d_ws;
  unsigned short* xFh  = wsu + OFF_XFH;
  unsigned short* wF1h = wsu + OFF_WPH;
  unsigned short* wF1l = wsu + OFF_WPL;
  unsigned short* wF2  = wsu + OFF_WCH;
  float* planes = (float*)((char*)d_ws + FIXED_BYTES);

  const size_t ws_per_batch = (size_t)NTOT * HW * sizeof(float);  // 28.3 MB
  size_t avail = (ws_size > FIXED_BYTES) ? (ws_size - FIXED_BYTES) : 0;
  int nb = (int)(avail / ws_per_batch);
  if (nb < 1) nb = 1;
  if (nb > NBATCH) nb = NBATCH;

  prep_x<<<dim3(HXW, NBATCH), TCNT, 0, stream>>>(x, xFh);
  prep_w<<<dim3(NGT, 18), TCNT, 0, stream>>>(w_off, w_mod, wF1h, wF1l);
  prep_wc<<<dim3(8, 18), TCNT, 0, stream>>>(w_conv, wF2);

  for (int b0 = 0; b0 < NBATCH; b0 += nb) {
    const int cur = (NBATCH - b0 < nb) ? (NBATCH - b0) : nb;
    dim3 g1(cur * 32, 14);   // pixel tiles x co tiles (14*128 = 1792 >= 1728)
    dcn_stage1<<<g1, TCNT, 0, stream>>>(xFh, wF1h, wF1l, b_off, b_mod,
                                        planes, b0, cur);
    dcn_stage2<<<cur * 128, TCNT, 0, stream>>>(x, planes, wF2, out, b0, cur);
  }
}